// Round 4
// baseline (54.055 us; speedup 1.0000x reference)
//
#include <hip/hip_runtime.h>

// DiversityLoss: pose (K=32, B=32, T=64, E=63) fp32.
// feat[bt,k,e] = pose[k, b, t, e], bt = b*64+t.
// loss = sum_{bt} sum_{i<j} exp(-L1(feat[bt,i], feat[bt,j])) / (BT*K*(K-1)/2)
// Off-diagonal sum computed directly (both triangles, then halve) — diagonal
// exp(0)=1 terms would absorb the ~1e-18 off-diagonal terms in fp32.
//
// 1 block (256 thr, 4 waves) per bt slice; waves split the e-dim (16 elems
// each) keeping the 4x4 register tile (0.5 LDS-reads/pair). Per-wave partial
// acc[4][4] exchanged as float4 (conflict-free b128). Final 2048->1 reduce is
// fused via the last-block pattern: counter in d_ws zeroed by hipMemsetAsync
// each call; agent-scope atomics/loads for cross-XCD visibility (G16).

#define KDIM 32
#define EDIM 63
#define STRIDE 68      // feat row stride (dwords): 16B-aligned; 68%32=4 spreads rows over banks
#define BT_TOTAL 2048
#define CNT 1015808.0f // 2048 * 32*31/2

__global__ __launch_bounds__(256) void divloss_fused(const float* __restrict__ pose,
                                                     float* __restrict__ ws,
                                                     unsigned* __restrict__ counter,
                                                     float* __restrict__ out) {
    // 16 KB: feat tile (32*68 = 2176 dw) aliases part4 (1024 float4 = 4096 dw).
    __shared__ float smem[4096];
    __shared__ float wsum[4];
    __shared__ int lastflag;
    float* feat = smem;
    float4* part4 = reinterpret_cast<float4*>(smem);

    const int bt = blockIdx.x;
    const int wv = threadIdx.x >> 6;    // 0..3
    const int lane = threadIdx.x & 63;  // 0..63

    // Stage feat[bt]: wave wv loads rows 8*wv .. 8*wv+7 (63 floats, pad e=63 with 0).
    #pragma unroll
    for (int r = 0; r < 8; ++r) {
        const int k = 8 * wv + r;
        float v = 0.0f;
        if (lane < EDIM) v = pose[(k * BT_TOTAL + bt) * EDIM + lane];
        feat[k * STRIDE + lane] = v;
    }
    __syncthreads();

    const int ti = lane >> 3;   // rows {ti, ti+8, ti+16, ti+24}
    const int tj = lane & 7;    // cols {tj, tj+8, tj+16, tj+24}

    float acc[4][4] = {};

    // Wave wv covers e-chunks 4*wv .. 4*wv+3 (16 e-elems; wave 3 includes the pad).
    #pragma unroll
    for (int i = 0; i < 4; ++i) {
        const int ec = 4 * wv + i;
        float4 a[4], b[4];
        #pragma unroll
        for (int r = 0; r < 4; ++r)
            a[r] = *reinterpret_cast<const float4*>(&feat[(ti + 8 * r) * STRIDE + 4 * ec]);
        #pragma unroll
        for (int c = 0; c < 4; ++c)
            b[c] = *reinterpret_cast<const float4*>(&feat[(tj + 8 * c) * STRIDE + 4 * ec]);
        #pragma unroll
        for (int r = 0; r < 4; ++r)
            #pragma unroll
            for (int c = 0; c < 4; ++c) {
                acc[r][c] += fabsf(a[r].x - b[c].x) + fabsf(a[r].y - b[c].y)
                           + fabsf(a[r].z - b[c].z) + fabsf(a[r].w - b[c].w);
            }
    }

    __syncthreads();   // all feat reads done; safe to overwrite with partials

    // Exchange: wave wv writes acc[r][0..3] as one float4 at entry (wv*4+r).
    // Lane stride 16B -> conflict-free ds_write_b128.
    #pragma unroll
    for (int r = 0; r < 4; ++r)
        part4[(wv * 4 + r) * 64 + lane] = make_float4(acc[r][0], acc[r][1], acc[r][2], acc[r][3]);
    __syncthreads();

    // Wave wv finalizes rows r=wv: d[c] = sum over source waves of partials.
    float d0 = 0.f, d1 = 0.f, d2 = 0.f, d3 = 0.f;
    #pragma unroll
    for (int sw = 0; sw < 4; ++sw) {
        float4 v = part4[(sw * 4 + wv) * 64 + lane];
        d0 += v.x; d1 += v.y; d2 += v.z; d3 += v.w;
    }
    // exp, mask diagonal pairs (ti==tj && c==wv), accumulate.
    float s = 0.0f;
    {
        float e0 = __expf(-d0), e1 = __expf(-d1), e2 = __expf(-d2), e3 = __expf(-d3);
        s += ((ti == tj) && (wv == 0)) ? 0.0f : e0;
        s += ((ti == tj) && (wv == 1)) ? 0.0f : e1;
        s += ((ti == tj) && (wv == 2)) ? 0.0f : e2;
        s += ((ti == tj) && (wv == 3)) ? 0.0f : e3;
    }

    #pragma unroll
    for (int off = 32; off > 0; off >>= 1) s += __shfl_down(s, off, 64);
    if (lane == 0) wsum[wv] = s;
    __syncthreads();

    if (threadIdx.x == 0) {
        float bsum = 0.5f * (wsum[0] + wsum[1] + wsum[2] + wsum[3]);
        __hip_atomic_store(&ws[bt], bsum, __ATOMIC_RELAXED, __HIP_MEMORY_SCOPE_AGENT);
        unsigned old = __hip_atomic_fetch_add(counter, 1u, __ATOMIC_ACQ_REL,
                                              __HIP_MEMORY_SCOPE_AGENT);
        lastflag = (old == (unsigned)(BT_TOTAL - 1)) ? 1 : 0;
    }
    __syncthreads();

    // Last block (block-uniform branch) does the final 2048 -> 1 reduce.
    if (lastflag) {
        float t = 0.0f;
        for (int i = threadIdx.x; i < BT_TOTAL; i += 256)
            t += __hip_atomic_load(&ws[i], __ATOMIC_RELAXED, __HIP_MEMORY_SCOPE_AGENT);
        #pragma unroll
        for (int off = 32; off > 0; off >>= 1) t += __shfl_down(t, off, 64);
        if (lane == 0) wsum[wv] = t;
        __syncthreads();
        if (threadIdx.x == 0)
            out[0] = (wsum[0] + wsum[1] + wsum[2] + wsum[3]) * (1.0f / CNT);
    }
}

extern "C" void kernel_launch(void* const* d_in, const int* in_sizes, int n_in,
                              void* d_out, int out_size, void* d_ws, size_t ws_size,
                              hipStream_t stream) {
    const float* pose = (const float*)d_in[0];
    float* out = (float*)d_out;
    float* ws = (float*)d_ws;                              // 2048 partials
    unsigned* counter = (unsigned*)((char*)d_ws + BT_TOTAL * sizeof(float));

    hipMemsetAsync(counter, 0, sizeof(unsigned), stream);  // graph-capturable node
    divloss_fused<<<BT_TOTAL, 256, 0, stream>>>(pose, ws, counter, out);
}